// Round 4
// baseline (7535.587 us; speedup 1.0000x reference)
//
#include <hip/hip_runtime.h>
#include <stdint.h>

typedef unsigned short ushort_t;
typedef __bf16 bf16x8 __attribute__((ext_vector_type(8)));
typedef float f32x4 __attribute__((ext_vector_type(4)));

// ---------- bf16 <-> f32 (bit ops) ----------
__device__ __forceinline__ float b2f(ushort_t u) {
  union { unsigned u; float f; } v; v.u = ((unsigned)u) << 16; return v.f;
}
__device__ __forceinline__ ushort_t f2b(float f) {
  union { float f; unsigned u; } v; v.f = f;
  unsigned r = (v.u + 0x7FFFu + ((v.u >> 16) & 1u)) >> 16;
  return (ushort_t)r;
}

// =====================================================================
// GEMM: C[M,N] = A[M,K] @ B[N,K]^T + bias0 + bias1 (bf16 in, f32 acc,
// bf16 or f32 out). BM=BN=128, BK=32, 256 thr (4 waves), reg-staged LDS.
// Requires: M%128==0, Kpad%32==0, lda/ldb%8==0, B zero-padded to gridDim.y*128 rows.
// =====================================================================
template <bool F32OUT>
__global__ __launch_bounds__(256) void gemm_bt(
    const ushort_t* __restrict__ A, const ushort_t* __restrict__ B,
    void* __restrict__ Cv,
    const float* __restrict__ bias0, const float* __restrict__ bias1,
    int lda, int ldb, int ldc, int Kpad, int N)
{
  __shared__ alignas(16) ushort_t As[128 * 32];
  __shared__ alignas(16) ushort_t Bs[128 * 32];
  const int tid = threadIdx.x;
  const int w = tid >> 6, l = tid & 63;
  const int wr = w >> 1, wc = w & 1;
  const long m0 = (long)blockIdx.x * 128;
  const long n0 = (long)blockIdx.y * 128;
  const int lrow = l & 15, lk = (l >> 4) * 8;

  f32x4 acc[4][4] = {};

  // chunk c <-> tile row c/4, ushort col (c%4)*8; LDS linear offset c*8 ushorts
  const int c0 = tid, c1 = tid + 256;
  const int r0 = c0 >> 2, g0 = (c0 & 3) * 8;
  const int r1 = c1 >> 2, g1 = (c1 & 3) * 8;

  for (int k0 = 0; k0 < Kpad; k0 += 32) {
    bf16x8 a0 = *(const bf16x8*)(A + (m0 + r0) * lda + k0 + g0);
    bf16x8 a1 = *(const bf16x8*)(A + (m0 + r1) * lda + k0 + g1);
    bf16x8 b0 = *(const bf16x8*)(B + (n0 + r0) * ldb + k0 + g0);
    bf16x8 b1 = *(const bf16x8*)(B + (n0 + r1) * ldb + k0 + g1);
    __syncthreads();   // previous iteration's LDS consumers done
    *(bf16x8*)(As + c0 * 8) = a0;
    *(bf16x8*)(As + c1 * 8) = a1;
    *(bf16x8*)(Bs + c0 * 8) = b0;
    *(bf16x8*)(Bs + c1 * 8) = b1;
    __syncthreads();

    bf16x8 af[4], bfr[4];
#pragma unroll
    for (int mi = 0; mi < 4; mi++)
      af[mi] = *(const bf16x8*)(As + (wr * 64 + mi * 16 + lrow) * 32 + lk);
#pragma unroll
    for (int ni = 0; ni < 4; ni++)
      bfr[ni] = *(const bf16x8*)(Bs + (wc * 64 + ni * 16 + lrow) * 32 + lk);
#pragma unroll
    for (int mi = 0; mi < 4; mi++)
#pragma unroll
      for (int ni = 0; ni < 4; ni++)
        acc[mi][ni] = __builtin_amdgcn_mfma_f32_16x16x32_bf16(af[mi], bfr[ni], acc[mi][ni], 0, 0, 0);
  }

  // epilogue: D layout col=lane&15, row=(lane>>4)*4+reg  [guide §3, m89]
  const int rbase = (l >> 4) * 4;
#pragma unroll
  for (int ni = 0; ni < 4; ni++) {
    int gcol = (int)n0 + wc * 64 + ni * 16 + lrow;
    if (gcol < N) {
      float badd = 0.f;
      if (bias0) badd += bias0[gcol];
      if (bias1) badd += bias1[gcol];
#pragma unroll
      for (int mi = 0; mi < 4; mi++) {
#pragma unroll
        for (int r = 0; r < 4; r++) {
          long grow = m0 + wr * 64 + mi * 16 + rbase + r;
          float v = acc[mi][ni][r] + badd;
          if (F32OUT) ((float*)Cv)[grow * ldc + gcol] = v;
          else        ((ushort_t*)Cv)[grow * ldc + gcol] = f2b(v);
        }
      }
    }
  }
}

// =====================================================================
// One LSTM time step: gates = G[t] + h_{t-1} @ Whh^T ; cell update -> hs[t+1]
// =====================================================================
__global__ __launch_bounds__(256) void lstm_step(
    ushort_t* __restrict__ hs,        // [101][64][1152] bf16
    const ushort_t* __restrict__ G,   // [6400][4608] bf16 (x@Wih^T + biases)
    const ushort_t* __restrict__ Whh, // padded [4608][1152] bf16
    float* __restrict__ c_ws,         // [64][1150] f32
    int t)
{
  __shared__ float sg[4][16][16];
  const int tid = threadIdx.x;
  const int w = tid >> 6, l = tid & 63;
  const int bt = blockIdx.x, us = blockIdx.y;
  const int lrow = l & 15, lk = (l >> 4) * 8;

  const ushort_t* hprev = hs + (long)t * 64 * 1152;
  const ushort_t* aP = hprev + (long)(bt * 16 + lrow) * 1152 + lk;
  const ushort_t* bP = Whh + (long)(w * 1150 + us * 16 + lrow) * 1152 + lk;

  f32x4 acc = {};
#pragma unroll 6
  for (int kc = 0; kc < 36; kc++) {
    bf16x8 a = *(const bf16x8*)(aP + kc * 32);
    bf16x8 b = *(const bf16x8*)(bP + kc * 32);
    acc = __builtin_amdgcn_mfma_f32_16x16x32_bf16(a, b, acc, 0, 0, 0);
  }

  const int rbase = (l >> 4) * 4;
#pragma unroll
  for (int r = 0; r < 4; r++) {
    int brow = bt * 16 + rbase + r;
    int u = us * 16 + lrow;
    float v = acc[r];
    if (u < 1150) v += b2f(G[(long)(t * 64 + brow) * 4608 + w * 1150 + u]);
    sg[w][rbase + r][lrow] = v;
  }
  __syncthreads();

  int row = tid >> 4, ul = tid & 15;
  int u = us * 16 + ul;
  if (u < 1150) {
    int b = bt * 16 + row;
    float iv = sg[0][row][ul], fv = sg[1][row][ul];
    float gv = sg[2][row][ul], ov = sg[3][row][ul];
    float c_old = c_ws[b * 1150 + u];
    float ig = 1.f / (1.f + expf(-iv));
    float fg = 1.f / (1.f + expf(-fv));
    float gg = tanhf(gv);
    float cn = fg * c_old + ig * gg;
    float hv = (1.f / (1.f + expf(-ov))) * tanhf(cn);
    c_ws[b * 1150 + u] = cn;
    hs[(long)(t + 1) * 64 * 1152 + b * 1152 + u] = f2b(hv);
  }
}

// =====================================================================
// Fused causal attention for one (t,b): scores -> softmax -> PV. f32 math.
// =====================================================================
__global__ __launch_bounds__(256) void attn_kernel(
    const ushort_t* __restrict__ hs2,  // base at hs[1]: [100][64][1152] bf16
    ushort_t* __restrict__ outp)       // [6400][1152] bf16
{
  __shared__ float qf[1152];
  __shared__ float sc[104];
  __shared__ float sinv;
  const int rowi = blockIdx.x;  // t*64 + b
  const int t = rowi >> 6, b = rowi & 63;
  const int tid = threadIdx.x;
  const int w = tid >> 6, l = tid & 63;

  const ushort_t* q = hs2 + (long)rowi * 1152;
  for (int c = tid; c < 1150; c += 256) qf[c] = b2f(q[c]);
  __syncthreads();

  for (int s = w; s <= t; s += 4) {
    const ushort_t* k = hs2 + (long)(s * 64 + b) * 1152;
    float p = 0.f;
    for (int h = l; h < 1150; h += 64) p += qf[h] * b2f(k[h]);
    for (int off = 32; off; off >>= 1) p += __shfl_down(p, off);
    if (l == 0) sc[s] = p;
  }
  __syncthreads();

  if (w == 0) {
    float m = -1e30f;
    for (int s = l; s <= t; s += 64) m = fmaxf(m, sc[s]);
    for (int off = 32; off; off >>= 1) m = fmaxf(m, __shfl_down(m, off));
    m = __shfl(m, 0);
    float sum = 0.f;
    for (int s = l; s <= t; s += 64) { float e = expf(sc[s] - m); sc[s] = e; sum += e; }
    for (int off = 32; off; off >>= 1) sum += __shfl_down(sum, off);
    if (l == 0) sinv = 1.f / sum;
  }
  __syncthreads();

  const float si = sinv;
  for (int h = tid; h < 1150; h += 256) {
    float a = 0.f;
    for (int s = 0; s <= t; s++) a += sc[s] * b2f(hs2[(long)(s * 64 + b) * 1152 + h]);
    outp[(long)rowi * 1152 + h] = f2b(a * si);
  }
  if (tid < 2) outp[(long)rowi * 1152 + 1150 + tid] = 0;  // zero K-pad for decoder
}

// ---------- f32 -> bf16 conversion helpers ----------
__global__ void embed_kernel(const int* __restrict__ in1, const int* __restrict__ in2,
                             const float* __restrict__ emb, ushort_t* __restrict__ x0)
{
  int rowi = blockIdx.x;  // t*64+b
  int l = threadIdx.x;    // 64 threads
  long r1 = (long)in1[rowi] * 400, r2 = (long)in2[rowi] * 400;
  ushort_t* d = x0 + (long)rowi * 800;
  for (int c = l; c < 800; c += 64)
    d[c] = f2b(c < 400 ? emb[r1 + c] : emb[r2 + c - 400]);
}

__global__ void pad_convert(const float* __restrict__ in, ushort_t* __restrict__ out,
                            int R, int Cin, int total, int Cp)
{
  int idx = blockIdx.x * 256 + threadIdx.x;
  if (idx >= total) return;
  int r = idx / Cp, c = idx - r * Cp;
  float v = (r < R && c < Cin) ? in[(long)r * Cin + c] : 0.f;
  out[idx] = f2b(v);
}

__global__ void init_state(const float* __restrict__ h_in, const float* __restrict__ c_in,
                           ushort_t* __restrict__ hs, float* __restrict__ c_ws)
{
  int idx = blockIdx.x * 256 + threadIdx.x;  // grid covers 64*1152 = 73728
  if (idx < 64 * 1152) {
    int b = idx / 1152, c = idx - b * 1152;
    hs[idx] = (c < 1150) ? f2b(h_in[b * 1150 + c]) : (ushort_t)0;
  }
  if (idx < 64 * 1150) c_ws[idx] = c_in[idx];
  if (idx < 100 * 128) {  // zero K-pad cols of hs rows 1..100
    int t = idx >> 7, r = idx & 127, b = r >> 1, k = r & 1;
    hs[(long)(t + 1) * 64 * 1152 + b * 1152 + 1150 + k] = 0;
  }
}

// =====================================================================
extern "C" void kernel_launch(void* const* d_in, const int* in_sizes, int n_in,
                              void* d_out, int out_size, void* d_ws, size_t ws_size,
                              hipStream_t stream) {
  (void)in_sizes; (void)n_in; (void)out_size; (void)ws_size;
  const int* input  = (const int*)d_in[0];
  const int* input2 = (const int*)d_in[1];
  const float* h_in[3] = {(const float*)d_in[2], (const float*)d_in[4], (const float*)d_in[6]};
  const float* c_in[3] = {(const float*)d_in[3], (const float*)d_in[5], (const float*)d_in[7]};
  const float* emb_W = (const float*)d_in[8];
  const float* W_ih[3] = {(const float*)d_in[9],  (const float*)d_in[13], (const float*)d_in[17]};
  const float* W_hh[3] = {(const float*)d_in[10], (const float*)d_in[14], (const float*)d_in[18]};
  const float* b_ih[3] = {(const float*)d_in[11], (const float*)d_in[15], (const float*)d_in[19]};
  const float* b_hh[3] = {(const float*)d_in[12], (const float*)d_in[16], (const float*)d_in[20]};
  const float* dec_W = (const float*)d_in[21];
  const float* dec_b = (const float*)d_in[22];
  float* out = (float*)d_out;

  // ---- workspace: only buffers alive during the final decoder GEMM (91.7 MB) ----
  char* base = (char*)d_ws;
  size_t off = 0;
  auto walloc = [&](size_t bytes) { char* r = base + off; off += (bytes + 255) & ~(size_t)255; return r; };
  ushort_t* decWp = (ushort_t*)walloc(33280ull * 1152 * 2);   // 76,677,120
  ushort_t* attnB = (ushort_t*)walloc(6400ull * 1152 * 2);    // 14,745,600
  float*    c_ws  = (float*)walloc(64ull * 1150 * 4);         //    294,400

  // ---- layer-phase scratch inside d_out (852 MB f32; scratch uses first
  //      ~120 MB, all dead before the decoder GEMM which reads only ws and
  //      rewrites every element of d_out). ----
  char* ob = (char*)d_out;
  ushort_t* G   = (ushort_t*)(ob + 0);            // 6400*4608*2 = 58,982,400
  ushort_t* x0  = (ushort_t*)(ob + 58982400);     // 6400*800*2  = 10,240,000
  ushort_t* Wp  = (ushort_t*)(ob + 69222400);     // 4608*1152*2 = 10,616,832
  ushort_t* Whp = (ushort_t*)(ob + 79839232);     // 4608*1152*2 = 10,616,832
  ushort_t* hsA = (ushort_t*)(ob + 90456064);     // 101*64*1152*2 = 14,893,056
  ushort_t* hsB = (ushort_t*)(ob + 105349120);    // 14,893,056 -> end 120,242,176

  // ---- embedding (f32 gather -> bf16) ----
  embed_kernel<<<6400, 64, 0, stream>>>(input, input2, emb_W, x0);

  // ---- 3 LSTM layers (hs ping-pong: L0->hsA, L1: hsA->hsB, L2: hsB->hsA) ----
  ushort_t* hcur[3] = {hsA, hsB, hsA};
  const ushort_t* X = x0;
  int lda = 800, Kp = 800;
  for (int lyr = 0; lyr < 3; lyr++) {
    if (lyr == 0) {
      int tot = 4608 * 800;
      pad_convert<<<(tot + 255) / 256, 256, 0, stream>>>(W_ih[0], Wp, 4600, 800, tot, 800);
    } else {
      int tot = 4608 * 1152;
      pad_convert<<<(tot + 255) / 256, 256, 0, stream>>>(W_ih[lyr], Wp, 4600, 1150, tot, 1152);
    }
    {
      int tot = 4608 * 1152;
      pad_convert<<<(tot + 255) / 256, 256, 0, stream>>>(W_hh[lyr], Whp, 4600, 1150, tot, 1152);
    }
    gemm_bt<false><<<dim3(50, 36), 256, 0, stream>>>(X, Wp, (void*)G, b_ih[lyr], b_hh[lyr],
                                                     lda, Kp, 4608, Kp, 4600);
    init_state<<<288, 256, 0, stream>>>(h_in[lyr], c_in[lyr], hcur[lyr], c_ws);
    for (int t = 0; t < 100; t++)
      lstm_step<<<dim3(4, 72), 256, 0, stream>>>(hcur[lyr], G, Whp, c_ws, t);
    X = hcur[lyr] + 64 * 1152;  // hs[1..100] as next layer's input
    lda = 1152; Kp = 1152;
  }

  // ---- causal attention on layer-2 hidden states (hsA) -> attnB (ws) ----
  attn_kernel<<<6400, 256, 0, stream>>>(hsA + 64 * 1152, attnB);

  // ---- pad+convert decoder weight into ws ----
  {
    int tot = 33280 * 1152;
    pad_convert<<<(tot + 255) / 256, 256, 0, stream>>>(dec_W, decWp, 33278, 1150, tot, 1152);
  }

  // ---- decoder GEMM -> d_out (f32 out; reads only ws; overwrites all scratch) ----
  gemm_bt<true><<<dim3(50, 260), 256, 0, stream>>>(attnB, decWp, (void*)out, dec_b, nullptr,
                                                   1152, 1152, 33278, 1152, 33278);
}